// Round 2
// baseline (387.811 us; speedup 1.0000x reference)
//
#include <hip/hip_runtime.h>
#include <math.h>

// B=16, Cin=32, Cout=32, H=W=256, m1=m2=16; retained kx in {0..15, 240..255}, ky in {0..15}
#define CIN   32
#define COUT  32
#define TWO_PI 6.283185307179586f

typedef short short8 __attribute__((ext_vector_type(8)));
typedef float f32x4  __attribute__((ext_vector_type(4)));

__device__ __forceinline__ ushort f2bf(float v) {
    unsigned u = __float_as_uint(v);
    u += 0x7FFFu + ((u >> 16) & 1u);          // RNE to bf16
    return (ushort)(u >> 16);
}
__device__ __forceinline__ float bf2f(ushort h) {
    return __uint_as_float(((unsigned)h) << 16);
}

__global__ void init_tab(float2* __restrict__ tab) {
    int k = threadIdx.x;
    double a = (2.0 * M_PI / 256.0) * (double)k;
    tab[k] = make_float2((float)cos(a), (float)sin(a));
}

// ---------------- F1: row DFT via bf16 hi/lo MFMA ----------------
// T[R][2ky]   = sum_w x[R][w]*cos(2pi ky w/256)
// T[R][2ky+1] = sum_w x[R][w]*(-sin(2pi ky w/256))
// Block: 128 rows, K=256 in 8 chunks of 32. 4 waves x 2 M-tiles x 2 N-tiles.
__global__ __launch_bounds__(256) void fwd_rowdft(const float* __restrict__ x,
                                                  float* __restrict__ T) {
    __shared__ ushort Ah[128][32];     // 8 KB  bf16-hi of x chunk [row][k]
    __shared__ ushort Al[128][32];     // 8 KB  bf16-lo
    __shared__ ushort Bf[32 * 512];    // 32 KB frag-ordered twiddles: slot(tn,s,ch)*512 + lane*8 + j

    const int t = threadIdx.x;
    const size_t row0 = (size_t)blockIdx.x * 128;

    // Build B-frags once: B[k][c], c = 2*ky + (0:cos | 1:-sin), frag layout
    // lane holds B[k = q*8+j][n = lane&15] for tile tn (cols tn*16+n).
    {
        const int c = t & 31, tn = c >> 4, n = c & 15, ky = c >> 1;
        const int k0 = (t >> 5) * 32;
        for (int kk = 0; kk < 32; ++kk) {
            int k = k0 + kk;
            float ang = (float)((k * ky) & 255) * (TWO_PI / 256.0f);
            float v = (c & 1) ? -sinf(ang) : cosf(ang);
            ushort h = f2bf(v);
            ushort l = f2bf(v - bf2f(h));
            int lanef = ((k >> 3) & 3) * 16 + n;
            int ch = k >> 5, j = k & 7;
            Bf[(size_t)(((tn * 2 + 0) * 8 + ch) * 512 + lanef * 8 + j)] = h;
            Bf[(size_t)(((tn * 2 + 1) * 8 + ch) * 512 + lanef * 8 + j)] = l;
        }
    }

    const int srow = t >> 3;          // 0..31 staging row group
    const int sw4  = t & 7;           // staging float4 index
    const int lane = t & 63;
    const int wid  = t >> 6;          // wave id 0..3
    const int q    = lane >> 4;       // quad 0..3
    const int n    = lane & 15;

    f32x4 acc[2][2];
    #pragma unroll
    for (int mt = 0; mt < 2; ++mt)
        #pragma unroll
        for (int tn = 0; tn < 2; ++tn)
            acc[mt][tn] = (f32x4){0.f, 0.f, 0.f, 0.f};

    const short8* Bfv = (const short8*)Bf;

    for (int ch = 0; ch < 8; ++ch) {
        __syncthreads();   // prior chunk fully consumed (and B-build on ch=0)
        // stage 128 rows x 32 k of x as bf16 hi/lo
        #pragma unroll
        for (int m = 0; m < 4; ++m) {
            const int row = srow + 32 * m;
            float4 v = *(const float4*)(x + (row0 + row) * 256 + ch * 32 + sw4 * 4);
            ushort h0 = f2bf(v.x), h1 = f2bf(v.y), h2 = f2bf(v.z), h3 = f2bf(v.w);
            *(ushort4*)&Ah[row][sw4 * 4] = make_ushort4(h0, h1, h2, h3);
            *(ushort4*)&Al[row][sw4 * 4] = make_ushort4(f2bf(v.x - bf2f(h0)), f2bf(v.y - bf2f(h1)),
                                                        f2bf(v.z - bf2f(h2)), f2bf(v.w - bf2f(h3)));
        }
        __syncthreads();

        short8 bh0 = Bfv[(0 * 8 + ch) * 64 + lane];
        short8 bl0 = Bfv[(1 * 8 + ch) * 64 + lane];
        short8 bh1 = Bfv[(2 * 8 + ch) * 64 + lane];
        short8 bl1 = Bfv[(3 * 8 + ch) * 64 + lane];

        #pragma unroll
        for (int mt = 0; mt < 2; ++mt) {
            const int row = wid * 32 + mt * 16 + n;       // A row for this lane
            short8 ah = *(const short8*)&Ah[row][q * 8];
            short8 al = *(const short8*)&Al[row][q * 8];
            acc[mt][0] = __builtin_amdgcn_mfma_f32_16x16x32_bf16(al, bh0, acc[mt][0], 0, 0, 0);
            acc[mt][0] = __builtin_amdgcn_mfma_f32_16x16x32_bf16(ah, bl0, acc[mt][0], 0, 0, 0);
            acc[mt][0] = __builtin_amdgcn_mfma_f32_16x16x32_bf16(ah, bh0, acc[mt][0], 0, 0, 0);
            acc[mt][1] = __builtin_amdgcn_mfma_f32_16x16x32_bf16(al, bh1, acc[mt][1], 0, 0, 0);
            acc[mt][1] = __builtin_amdgcn_mfma_f32_16x16x32_bf16(ah, bl1, acc[mt][1], 0, 0, 0);
            acc[mt][1] = __builtin_amdgcn_mfma_f32_16x16x32_bf16(ah, bh1, acc[mt][1], 0, 0, 0);
        }
    }

    // epilogue: C/D layout col = lane&15, row = q*4 + reg
    #pragma unroll
    for (int mt = 0; mt < 2; ++mt) {
        const size_t gr = row0 + wid * 32 + mt * 16 + q * 4;
        #pragma unroll
        for (int r = 0; r < 4; ++r) {
            T[(gr + r) * 32 + n]      = acc[mt][0][r];
            T[(gr + r) * 32 + 16 + n] = acc[mt][1][r];
        }
    }
}

// ---------------- F2: column DFT over h -> X[32 kx][16 ky] per image ----------------
__global__ __launch_bounds__(256) void fwd_coldft(const float* __restrict__ T,
                                                  const float2* __restrict__ tab,
                                                  float2* __restrict__ X) {
    __shared__ float  Ts[256][32];    // 32 KB
    __shared__ float2 tabs[256];
    const int t = threadIdx.x;
    const int bi = blockIdx.x;
    tabs[t] = tab[t];
    {
        const float4* src = (const float4*)(T + (size_t)bi * 8192);
        float4* dst = (float4*)&Ts[0][0];
        #pragma unroll
        for (int p = 0; p < 8; ++p) dst[t + 256 * p] = src[t + 256 * p];
    }
    __syncthreads();
    const int ky = t & 15, kx = t >> 4;       // kx 0..15; also compute kx+16 (row kx+240)
    float x1r = 0.f, x1i = 0.f, x2r = 0.f, x2i = 0.f;
    int i1 = 0, i2 = 0;
    for (int h = 0; h < 256; ++h) {
        float2 tv = *(const float2*)&Ts[h][2 * ky];
        float2 c1 = tabs[i1];
        float2 c2 = tabs[i2];
        x1r = fmaf(tv.x, c1.x, fmaf( tv.y, c1.y, x1r));
        x1i = fmaf(tv.y, c1.x, fmaf(-tv.x, c1.y, x1i));
        x2r = fmaf(tv.x, c2.x, fmaf( tv.y, c2.y, x2r));
        x2i = fmaf(tv.y, c2.x, fmaf(-tv.x, c2.y, x2i));
        i1 = (i1 + kx) & 255;
        i2 = (i2 + kx + 240) & 255;
    }
    float2* Xp = X + (size_t)bi * 512;
    Xp[kx * 16 + ky]        = make_float2(x1r, x1i);
    Xp[(kx + 16) * 16 + ky] = make_float2(x2r, x2i);
}

// ---------------- mix: Y[b,o,kxi,ky] = sum_i X[b,i,kxi,ky] * W[i,o,kxi,ky] ----------------
__global__ __launch_bounds__(256) void mix(const float2* __restrict__ X,
                                           const float* __restrict__ w1r_, const float* __restrict__ w1i_,
                                           const float* __restrict__ w2r_, const float* __restrict__ w2i_,
                                           float2* __restrict__ Y) {
    int gid = blockIdx.x * 256 + threadIdx.x;  // (((b*32+o)*32+kxi)*16+ky)
    int ky  = gid & 15;
    int kxi = (gid >> 4) & 31;
    int o   = (gid >> 9) & 31;
    int b   = gid >> 14;
    const float* wr = (kxi < 16) ? w1r_ : w2r_;
    const float* wi = (kxi < 16) ? w1i_ : w2i_;
    int xx = kxi & 15;
    const float2* Xp  = X + (size_t)(b * CIN) * 512 + kxi * 16 + ky;
    const float*  wrp = wr + ((size_t)o * 16 + xx) * 16 + ky;
    const float*  wip = wi + ((size_t)o * 16 + xx) * 16 + ky;
    float yr = 0.f, yi = 0.f;
    #pragma unroll 8
    for (int i = 0; i < CIN; ++i) {
        float2 xv  = Xp[i * 512];
        float  wre = wrp[i * (COUT * 256)];
        float  wim = wip[i * (COUT * 256)];
        yr = fmaf(xv.x, wre, fmaf(-xv.y, wim, yr));
        yi = fmaf(xv.x, wim, fmaf( xv.y, wre, yi));
    }
    Y[gid] = make_float2(yr, yi);
}

// ---------------- I1: inverse column DFT -> G[b,o][256 h][16 ky] ----------------
__global__ __launch_bounds__(256) void inv_rowdft(const float2* __restrict__ Y,
                                                  const float2* __restrict__ tab,
                                                  float2* __restrict__ G) {
    __shared__ float2 Ys[512];
    __shared__ float2 tabs[256];
    const int t = threadIdx.x;
    const int bo = blockIdx.x;
    tabs[t] = tab[t];
    Ys[t]       = Y[(size_t)bo * 512 + t];
    Ys[t + 256] = Y[(size_t)bo * 512 + t + 256];
    __syncthreads();
    const int ky = t & 15, hg = t >> 4;      // hg 0..15
    float2 yv[32];
    #pragma unroll
    for (int kx = 0; kx < 32; ++kx) yv[kx] = Ys[kx * 16 + ky];
    const float norm = 1.0f / 65536.0f;
    for (int m = 0; m < 16; ++m) {
        const int h = hg * 16 + m;
        float gr = 0.f, gi = 0.f;
        #pragma unroll 8
        for (int kx = 0; kx < 32; ++kx) {
            const int r = (kx < 16) ? kx : (kx + 224);   // rows 0..15, 240..255
            float2 c = tabs[(r * h) & 255];
            float2 y = yv[kx];
            gr = fmaf(y.x, c.x, fmaf(-y.y, c.y, gr));    // e^{+i th}
            gi = fmaf(y.x, c.y, fmaf( y.y, c.x, gi));
        }
        G[(size_t)bo * 4096 + h * 16 + ky] = make_float2(gr * norm, gi * norm);
    }
}

// ---------------- I2: c2r along w, thread = w, twiddles in registers ----------------
__global__ __launch_bounds__(256) void inv_coldft(const float* __restrict__ G,
                                                  const float2* __restrict__ tab,
                                                  float* __restrict__ out) {
    __shared__ float2 tabs[256];
    const int t = threadIdx.x;
    const int bo = blockIdx.x >> 2;
    const int hc = blockIdx.x & 3;           // 64-row chunk
    tabs[t] = tab[t];
    __syncthreads();
    float2 tw[15];
    #pragma unroll
    for (int ky = 1; ky <= 15; ++ky) tw[ky - 1] = tabs[(t * ky) & 255];
    const float4* __restrict__ gp = (const float4*)(G + (size_t)bo * 8192 + hc * 64 * 32);
    float* __restrict__ op = out + (size_t)bo * 65536 + hc * 64 * 256 + t;
    for (int h = 0; h < 64; ++h) {
        float4 g4[8];
        #pragma unroll
        for (int p = 0; p < 8; ++p) g4[p] = gp[h * 8 + p];   // wave-uniform -> s_load
        const float* g = (const float*)g4;
        float s = 0.f;
        #pragma unroll
        for (int ky = 1; ky <= 15; ++ky)
            s = fmaf(g[2 * ky], tw[ky - 1].x, fmaf(-g[2 * ky + 1], tw[ky - 1].y, s));
        op[h * 256] = fmaf(2.f, s, g[0]);    // drop Im(g0), weight 1 for ky=0, 2 for ky>=1
    }
}

extern "C" void kernel_launch(void* const* d_in, const int* in_sizes, int n_in,
                              void* d_out, int out_size, void* d_ws, size_t ws_size,
                              hipStream_t stream) {
    const float* x   = (const float*)d_in[0];
    const float* w1r = (const float*)d_in[1];
    const float* w1i = (const float*)d_in[2];
    const float* w2r = (const float*)d_in[3];
    const float* w2i = (const float*)d_in[4];
    float* out = (float*)d_out;

    // ws: tab (2 KB) | T/G (16 MB, aliased) | X (2 MB) | Y (2 MB)  => ~21 MB
    float2* tab = (float2*)d_ws;
    float*  T   = (float*)(tab + 256);
    float2* X   = (float2*)(T + (size_t)131072 * 32);
    float2* Yb  = X + 262144;
    float2* G   = (float2*)T;          // lifetime of T ends before G is written

    init_tab  <<<1,    256, 0, stream>>>(tab);
    fwd_rowdft<<<1024, 256, 0, stream>>>(x, T);
    fwd_coldft<<<512,  256, 0, stream>>>(T, tab, X);
    mix       <<<1024, 256, 0, stream>>>(X, w1r, w1i, w2r, w2i, Yb);
    inv_rowdft<<<512,  256, 0, stream>>>(Yb, tab, G);
    inv_coldft<<<2048, 256, 0, stream>>>((const float*)G, tab, out);
}

// Round 3
// 315.714 us; speedup vs baseline: 1.2284x; 1.2284x over previous
//
#include <hip/hip_runtime.h>
#include <math.h>

// B=16, Cin=32, Cout=32, H=W=256, m1=m2=16; kept kx in {0..15,240..255}, ky in {0..15}
//
// Pipeline (all GEMMs bf16 hi/lo, 3-term MFMA):
//  F1:  T[h][reim][bi][ky]           = x[bi*256+h][w] . B1[w][reim*16+ky]          (M=131072,N=32,K=256)
//  F2:  X[kxi*2+reim][b*512+i*16+ky] = A2[m][h*2+reimT] . T                         (M=64,N=8192,K=512)
//  mix: Y[kxi*2+reim][b*512+o*16+ky] = sum_i X .* W   (fp32)
//  I1:  G[bo][h][ky*2+reim]          = A3[h*2+reim][kxi*2+reimY] . Y                (M=512,N=8192,K=64)
//  I2:  out[bo*256+h][w]             = G[R][ky*2+reim] . B2[k][w]                   (M=131072,N=256,K=32)
//
// Twiddle fragments precomputed frag-ordered in global ws (320 slots x 512 ushorts):
//  slot layout: Fr[slot*512 + lane*8 + j]; A-frag: lane holds A[m=lane&15][k=(lane>>4)*8+j]
//  B-frag: lane holds B[k=(lane>>4)*8+j][n=lane&15]   (both verified in earlier rounds)
//  slots: [0,32)=F1-B  (tn*16+hl*8+ch)     [32,160)=F2-A (32+mt*32+hl*16+ch)
//         [160,288)=I1-A (160+mtG*4+hl*2+ch)  [288,320)=I2-B (288+nt*2+hl)

#define TWO_PI_256 0.0245436926f

typedef short short8 __attribute__((ext_vector_type(8)));
typedef float f32x4  __attribute__((ext_vector_type(4)));

__device__ __forceinline__ ushort f2bf(float v) {
    unsigned u = __float_as_uint(v);
    u += 0x7FFFu + ((u >> 16) & 1u);
    return (ushort)(u >> 16);
}
__device__ __forceinline__ float bf2f(ushort h) {
    return __uint_as_float(((unsigned)h) << 16);
}

// ---------------- init: all twiddle fragments ----------------
__global__ void init_frags(ushort* __restrict__ Fr) {
    const int s = blockIdx.x;          // slot 0..319
    const int lane = threadIdx.x;      // 0..63
    const int q = lane >> 4, n = lane & 15;
    for (int j = 0; j < 8; ++j) {
        float v = 0.f;
        int hl;
        if (s < 32) {                          // F1 B: B[w][tn*16+ky]
            int tn = s >> 4; hl = (s >> 3) & 1; int ch = s & 7;
            int w = ch * 32 + q * 8 + j, ky = n;
            float sn, cs; __sincosf((float)((w * ky) & 255) * TWO_PI_256, &sn, &cs);
            v = tn == 0 ? cs : -sn;            // e^{-i}: Tr=+cos, Ti=-sin
        } else if (s < 160) {                  // F2 A: A[m][k], m=kxi*2+rx, k=h*2+rt
            int s2 = s - 32; int mt = s2 >> 5; hl = (s2 >> 4) & 1; int ch = s2 & 15;
            int m = mt * 16 + n, k = ch * 32 + q * 8 + j;
            int kxi = m >> 1, rx = m & 1, h = k >> 1, rt = k & 1;
            int r = kxi + (kxi >= 16 ? 224 : 0);
            float sn, cs; __sincosf((float)((r * h) & 255) * TWO_PI_256, &sn, &cs);
            v = (rx == 0) ? (rt == 0 ? cs : sn) : (rt == 0 ? -sn : cs);
        } else if (s < 288) {                  // I1 A: A[m][k], m=h*2+rg, k=kxi*2+ry (x 1/65536)
            int s3 = s - 160; int mtG = s3 >> 2; hl = (s3 >> 1) & 1; int ch = s3 & 1;
            int m = mtG * 16 + n, k = ch * 32 + q * 8 + j;
            int h = m >> 1, rg = m & 1, kxi = k >> 1, ry = k & 1;
            int r = kxi + (kxi >= 16 ? 224 : 0);
            float sn, cs; __sincosf((float)((r * h) & 255) * TWO_PI_256, &sn, &cs);
            v = ((rg == 0) ? (ry == 0 ? cs : -sn) : (ry == 0 ? sn : cs)) * (1.0f / 65536.0f);
        } else {                               // I2 B: B[k][w], k=ky*2+ri
            int s4 = s - 288; int nt = s4 >> 1; hl = s4 & 1;
            int k = q * 8 + j, w = nt * 16 + n;
            int ky = k >> 1, ri = k & 1;
            float sn, cs; __sincosf((float)((w * ky) & 255) * TWO_PI_256, &sn, &cs);
            v = (ky == 0) ? (ri ? 0.f : 1.f) : (ri ? -2.f * sn : 2.f * cs);
        }
        ushort hi = f2bf(v);
        Fr[s * 512 + lane * 8 + j] = hl == 0 ? hi : f2bf(v - bf2f(hi));
    }
}

// ---------------- F1: x -> T ----------------
__global__ __launch_bounds__(256) void f1_gemm(const float* __restrict__ x,
                                               const ushort* __restrict__ Fr,
                                               float* __restrict__ T) {
    __shared__ ushort Ah[128 * 32], Al[128 * 32];
    const int t = threadIdx.x, blk = blockIdx.x;
    const size_t row0 = (size_t)blk * 128;
    const int bi = blk >> 1, h0 = (blk & 1) * 128;
    const int srow = t >> 3, sw4 = t & 7;
    const int lane = t & 63, wid = t >> 6, q = lane >> 4, n = lane & 15;

    f32x4 acc[2][2];
    #pragma unroll
    for (int a = 0; a < 2; ++a)
        #pragma unroll
        for (int b = 0; b < 2; ++b) acc[a][b] = (f32x4){0.f, 0.f, 0.f, 0.f};

    for (int ch = 0; ch < 8; ++ch) {
        __syncthreads();
        #pragma unroll
        for (int m = 0; m < 4; ++m) {
            const int row = srow + 32 * m;
            float4 v = *(const float4*)(x + (row0 + row) * 256 + ch * 32 + sw4 * 4);
            ushort h0_ = f2bf(v.x), h1 = f2bf(v.y), h2 = f2bf(v.z), h3 = f2bf(v.w);
            *(ushort4*)&Ah[row * 32 + sw4 * 4] = make_ushort4(h0_, h1, h2, h3);
            *(ushort4*)&Al[row * 32 + sw4 * 4] = make_ushort4(f2bf(v.x - bf2f(h0_)), f2bf(v.y - bf2f(h1)),
                                                              f2bf(v.z - bf2f(h2)), f2bf(v.w - bf2f(h3)));
        }
        __syncthreads();

        short8 bh0 = *(const short8*)&Fr[(size_t)(0  + ch) * 512 + lane * 8];
        short8 bl0 = *(const short8*)&Fr[(size_t)(8  + ch) * 512 + lane * 8];
        short8 bh1 = *(const short8*)&Fr[(size_t)(16 + ch) * 512 + lane * 8];
        short8 bl1 = *(const short8*)&Fr[(size_t)(24 + ch) * 512 + lane * 8];

        #pragma unroll
        for (int mt = 0; mt < 2; ++mt) {
            const int row = wid * 32 + mt * 16 + n;
            short8 ah = *(const short8*)&Ah[row * 32 + q * 8];
            short8 al = *(const short8*)&Al[row * 32 + q * 8];
            acc[mt][0] = __builtin_amdgcn_mfma_f32_16x16x32_bf16(al, bh0, acc[mt][0], 0, 0, 0);
            acc[mt][0] = __builtin_amdgcn_mfma_f32_16x16x32_bf16(ah, bl0, acc[mt][0], 0, 0, 0);
            acc[mt][0] = __builtin_amdgcn_mfma_f32_16x16x32_bf16(ah, bh0, acc[mt][0], 0, 0, 0);
            acc[mt][1] = __builtin_amdgcn_mfma_f32_16x16x32_bf16(al, bh1, acc[mt][1], 0, 0, 0);
            acc[mt][1] = __builtin_amdgcn_mfma_f32_16x16x32_bf16(ah, bl1, acc[mt][1], 0, 0, 0);
            acc[mt][1] = __builtin_amdgcn_mfma_f32_16x16x32_bf16(ah, bh1, acc[mt][1], 0, 0, 0);
        }
    }
    // T[((h*2+tn)*512 + bi)*16 + ky]
    #pragma unroll
    for (int tn = 0; tn < 2; ++tn)
        #pragma unroll
        for (int mt = 0; mt < 2; ++mt)
            #pragma unroll
            for (int r = 0; r < 4; ++r) {
                int h = h0 + wid * 32 + mt * 16 + q * 4 + r;
                T[(size_t)((h * 2 + tn) * 512 + bi) * 16 + n] = acc[mt][tn][r];
            }
}

// ---------------- F2: T -> X ----------------
__global__ __launch_bounds__(256) void f2_gemm(const float* __restrict__ T,
                                               const ushort* __restrict__ Fr,
                                               float* __restrict__ X) {
    __shared__ ushort Bs[8 * 512];
    const int t = threadIdx.x;
    const int n0 = blockIdx.x * 64;
    const int lane = t & 63, wid = t >> 6, q = lane >> 4, nn = lane & 15;
    const int kk = t >> 3, ne = (t & 7) * 8, qk = kk >> 3, jk = kk & 7;

    f32x4 acc[4];
    #pragma unroll
    for (int m = 0; m < 4; ++m) acc[m] = (f32x4){0.f, 0.f, 0.f, 0.f};

    for (int ch = 0; ch < 16; ++ch) {
        __syncthreads();
        {
            float v[8];
            *(float4*)&v[0] = *(const float4*)&T[(size_t)(ch * 32 + kk) * 8192 + n0 + ne];
            *(float4*)&v[4] = *(const float4*)&T[(size_t)(ch * 32 + kk) * 8192 + n0 + ne + 4];
            #pragma unroll
            for (int e = 0; e < 8; ++e) {
                int nc = ne + e, nt = nc >> 4, lf = qk * 16 + (nc & 15);
                ushort hi = f2bf(v[e]);
                Bs[(nt * 2 + 0) * 512 + lf * 8 + jk] = hi;
                Bs[(nt * 2 + 1) * 512 + lf * 8 + jk] = f2bf(v[e] - bf2f(hi));
            }
        }
        __syncthreads();
        short8 bh = *(const short8*)&Bs[(wid * 2 + 0) * 512 + lane * 8];
        short8 bl = *(const short8*)&Bs[(wid * 2 + 1) * 512 + lane * 8];
        #pragma unroll
        for (int mt = 0; mt < 4; ++mt) {
            short8 ah = *(const short8*)&Fr[(size_t)(32 + mt * 32 + ch) * 512 + lane * 8];
            short8 al = *(const short8*)&Fr[(size_t)(32 + mt * 32 + 16 + ch) * 512 + lane * 8];
            acc[mt] = __builtin_amdgcn_mfma_f32_16x16x32_bf16(al, bh, acc[mt], 0, 0, 0);
            acc[mt] = __builtin_amdgcn_mfma_f32_16x16x32_bf16(ah, bl, acc[mt], 0, 0, 0);
            acc[mt] = __builtin_amdgcn_mfma_f32_16x16x32_bf16(ah, bh, acc[mt], 0, 0, 0);
        }
    }
    const int col = n0 + wid * 16 + nn;
    #pragma unroll
    for (int mt = 0; mt < 4; ++mt)
        #pragma unroll
        for (int r = 0; r < 4; ++r)
            X[(size_t)(mt * 16 + q * 4 + r) * 8192 + col] = acc[mt][r];
}

// ---------------- mix (fp32) ----------------
__global__ __launch_bounds__(256) void mix(const float* __restrict__ X,
                                           const float* __restrict__ w1r_, const float* __restrict__ w1i_,
                                           const float* __restrict__ w2r_, const float* __restrict__ w2i_,
                                           float* __restrict__ Y) {
    int gid = blockIdx.x * 256 + threadIdx.x;
    int ky = gid & 15, kxi = (gid >> 4) & 31, o = (gid >> 9) & 31, b = gid >> 14;
    const float* wr = (kxi < 16) ? w1r_ : w2r_;
    const float* wi = (kxi < 16) ? w1i_ : w2i_;
    int xx = kxi & 15;
    const float* Xr = X + (size_t)(kxi * 2) * 8192 + b * 512 + ky;
    const float* Xi = Xr + 8192;
    const float* wrp = wr + (size_t)(o * 16 + xx) * 16 + ky;
    const float* wip = wi + (size_t)(o * 16 + xx) * 16 + ky;
    float yr = 0.f, yi = 0.f;
    #pragma unroll 8
    for (int i = 0; i < 32; ++i) {
        float xr = Xr[i * 16], xim = Xi[i * 16];
        float wre = wrp[(size_t)i * 8192], wim = wip[(size_t)i * 8192];
        yr = fmaf(xr, wre, fmaf(-xim, wim, yr));
        yi = fmaf(xr, wim, fmaf( xim, wre, yi));
    }
    size_t yb = (size_t)(kxi * 2) * 8192 + b * 512 + o * 16 + ky;
    Y[yb] = yr;
    Y[yb + 8192] = yi;
}

// ---------------- I1: Y -> G ----------------
__global__ __launch_bounds__(256) void i1_gemm(const float* __restrict__ Yb,
                                               const ushort* __restrict__ Fr,
                                               float* __restrict__ G) {
    __shared__ ushort Bs[8 * 512];
    const int t = threadIdx.x;
    const int Mb = blockIdx.x & 3, n0 = (blockIdx.x >> 2) * 64;
    const int lane = t & 63, wid = t >> 6, q = lane >> 4, nn = lane & 15;
    const int kk = t >> 3, ne = (t & 7) * 8, qk = kk >> 3, jk = kk & 7;

    f32x4 acc[8];
    #pragma unroll
    for (int m = 0; m < 8; ++m) acc[m] = (f32x4){0.f, 0.f, 0.f, 0.f};

    for (int ch = 0; ch < 2; ++ch) {
        __syncthreads();
        {
            float v[8];
            *(float4*)&v[0] = *(const float4*)&Yb[(size_t)(ch * 32 + kk) * 8192 + n0 + ne];
            *(float4*)&v[4] = *(const float4*)&Yb[(size_t)(ch * 32 + kk) * 8192 + n0 + ne + 4];
            #pragma unroll
            for (int e = 0; e < 8; ++e) {
                int nc = ne + e, nt = nc >> 4, lf = qk * 16 + (nc & 15);
                ushort hi = f2bf(v[e]);
                Bs[(nt * 2 + 0) * 512 + lf * 8 + jk] = hi;
                Bs[(nt * 2 + 1) * 512 + lf * 8 + jk] = f2bf(v[e] - bf2f(hi));
            }
        }
        __syncthreads();
        short8 bh = *(const short8*)&Bs[(wid * 2 + 0) * 512 + lane * 8];
        short8 bl = *(const short8*)&Bs[(wid * 2 + 1) * 512 + lane * 8];
        #pragma unroll
        for (int mt = 0; mt < 8; ++mt) {
            int mtG = Mb * 8 + mt;
            short8 ah = *(const short8*)&Fr[(size_t)(160 + mtG * 4 + ch) * 512 + lane * 8];
            short8 al = *(const short8*)&Fr[(size_t)(160 + mtG * 4 + 2 + ch) * 512 + lane * 8];
            acc[mt] = __builtin_amdgcn_mfma_f32_16x16x32_bf16(al, bh, acc[mt], 0, 0, 0);
            acc[mt] = __builtin_amdgcn_mfma_f32_16x16x32_bf16(ah, bl, acc[mt], 0, 0, 0);
            acc[mt] = __builtin_amdgcn_mfma_f32_16x16x32_bf16(ah, bh, acc[mt], 0, 0, 0);
        }
    }
    // G[bo*8192 + h*32 + ky*2 + reim]  (pairs r=2rp,2rp+1 are re/im of one h)
    const int ncol = n0 + wid * 16 + nn;
    const int b = ncol >> 9, o = (ncol >> 4) & 31, ky = ncol & 15;
    const size_t gbase = (size_t)(b * 32 + o) * 8192 + ky * 2;
    #pragma unroll
    for (int mt = 0; mt < 8; ++mt)
        #pragma unroll
        for (int rp = 0; rp < 2; ++rp) {
            int h = (Mb * 8 + mt) * 8 + q * 2 + rp;
            *(float2*)&G[gbase + (size_t)h * 32] = make_float2(acc[mt][rp * 2], acc[mt][rp * 2 + 1]);
        }
}

// ---------------- I2: G -> out ----------------
__global__ __launch_bounds__(256) void i2_gemm(const float* __restrict__ G,
                                               const ushort* __restrict__ Fr,
                                               float* __restrict__ out) {
    __shared__ ushort As[8 * 512];
    const int t = threadIdx.x;
    const size_t R0 = (size_t)blockIdx.x * 64;
    const int lane = t & 63, wid = t >> 6, q = lane >> 4, nn = lane & 15;
    {
        const int row = t >> 2, qd = t & 3;
        float v[8];
        *(float4*)&v[0] = *(const float4*)&G[(R0 + row) * 32 + qd * 8];
        *(float4*)&v[4] = *(const float4*)&G[(R0 + row) * 32 + qd * 8 + 4];
        ushort hi8[8], lo8[8];
        #pragma unroll
        for (int e = 0; e < 8; ++e) {
            hi8[e] = f2bf(v[e]);
            lo8[e] = f2bf(v[e] - bf2f(hi8[e]));
        }
        const int mt = row >> 4, lf = qd * 16 + (row & 15);
        *(short8*)&As[(mt * 2 + 0) * 512 + lf * 8] = *(short8*)hi8;
        *(short8*)&As[(mt * 2 + 1) * 512 + lf * 8] = *(short8*)lo8;
    }
    __syncthreads();
    short8 ah = *(const short8*)&As[(wid * 2 + 0) * 512 + lane * 8];
    short8 al = *(const short8*)&As[(wid * 2 + 1) * 512 + lane * 8];

    f32x4 acc[16];
    #pragma unroll
    for (int m = 0; m < 16; ++m) acc[m] = (f32x4){0.f, 0.f, 0.f, 0.f};
    #pragma unroll
    for (int ntg = 0; ntg < 4; ++ntg) {
        #pragma unroll
        for (int u = 0; u < 4; ++u) {
            int nt = ntg * 4 + u;
            short8 bh = *(const short8*)&Fr[(size_t)(288 + nt * 2 + 0) * 512 + lane * 8];
            short8 bl = *(const short8*)&Fr[(size_t)(288 + nt * 2 + 1) * 512 + lane * 8];
            acc[nt] = __builtin_amdgcn_mfma_f32_16x16x32_bf16(al, bh, acc[nt], 0, 0, 0);
            acc[nt] = __builtin_amdgcn_mfma_f32_16x16x32_bf16(ah, bl, acc[nt], 0, 0, 0);
            acc[nt] = __builtin_amdgcn_mfma_f32_16x16x32_bf16(ah, bh, acc[nt], 0, 0, 0);
        }
    }
    const size_t Rrow = R0 + wid * 16 + q * 4;
    #pragma unroll
    for (int nt = 0; nt < 16; ++nt)
        #pragma unroll
        for (int r = 0; r < 4; ++r)
            out[(Rrow + r) * 256 + nt * 16 + nn] = acc[nt][r];
}

extern "C" void kernel_launch(void* const* d_in, const int* in_sizes, int n_in,
                              void* d_out, int out_size, void* d_ws, size_t ws_size,
                              hipStream_t stream) {
    const float* x   = (const float*)d_in[0];
    const float* w1r = (const float*)d_in[1];
    const float* w1i = (const float*)d_in[2];
    const float* w2r = (const float*)d_in[3];
    const float* w2i = (const float*)d_in[4];
    float* out = (float*)d_out;

    // ws: Fr 320KB @0 | T 16MB @1MB | X 2MB | Y 2MB | G 16MB
    ushort* Fr = (ushort*)d_ws;
    float*  T  = (float*)((char*)d_ws + (1u << 20));
    float*  X  = T + (size_t)4194304;
    float*  Yb = X + (size_t)524288;
    float*  G  = Yb + (size_t)524288;

    init_frags<<<320,  64,  0, stream>>>(Fr);
    f1_gemm   <<<1024, 256, 0, stream>>>(x, Fr, T);
    f2_gemm   <<<128,  256, 0, stream>>>(T, Fr, X);
    mix       <<<1024, 256, 0, stream>>>(X, w1r, w1i, w2r, w2i, Yb);
    i1_gemm   <<<512,  256, 0, stream>>>(Yb, Fr, G);
    i2_gemm   <<<2048, 256, 0, stream>>>(G, Fr, out);
}